// Round 1
// baseline (650.235 us; speedup 1.0000x reference)
//
#include <hip/hip_runtime.h>
#include <math.h>

// Problem constants (from reference): B=64, T=200, Q=4096
#define PB 64
#define PT 200
#define PQ 4096
#define PTM1 199

// Kernel 1: one block per (b, t) with t in [1, T-1].
// Computes over batch row t: sc = sum of cor half, si = sum of inc half,
// and sp = dot(pred[b, t-1, :], cor+inc).
__global__ __launch_bounds__(256) void row_reduce_kernel(
    const float* __restrict__ pred,    // (B, T, Q)
    const float* __restrict__ batch,   // (B, T, 2Q)
    float* __restrict__ p_ws,          // (B, TM1)
    float* __restrict__ flag_ws,       // (B, TM1)
    float* __restrict__ a_ws)          // (B, TM1)
{
    const int bt = blockIdx.x;
    const int b  = bt / PTM1;
    const int tm = bt - b * PTM1;   // 0..198  (output index)
    const int t  = tm + 1;          // batch row index

    const float4* cor = (const float4*)(batch + ((size_t)(b * PT + t)) * (2 * PQ));
    const float4* inc = cor + (PQ / 4);
    const float4* pr  = (const float4*)(pred + ((size_t)(b * PT + tm)) * PQ);

    float sc = 0.0f, si = 0.0f, sp = 0.0f;
    for (int i = threadIdx.x; i < PQ / 4; i += blockDim.x) {
        float4 c = cor[i];
        float4 n = inc[i];
        float4 pv = pr[i];
        sc += c.x + c.y + c.z + c.w;
        si += n.x + n.y + n.z + n.w;
        sp += pv.x * (c.x + n.x) + pv.y * (c.y + n.y)
            + pv.z * (c.z + n.z) + pv.w * (c.w + n.w);
    }

    // wave (64-lane) reduction
    for (int off = 32; off > 0; off >>= 1) {
        sc += __shfl_down(sc, off);
        si += __shfl_down(si, off);
        sp += __shfl_down(sp, off);
    }
    __shared__ float s0[4], s1[4], s2[4];
    const int lane = threadIdx.x & 63;
    const int wv   = threadIdx.x >> 6;
    if (lane == 0) { s0[wv] = sc; s1[wv] = si; s2[wv] = sp; }
    __syncthreads();
    if (threadIdx.x == 0) {
        sc = s0[0] + s0[1] + s0[2] + s0[3];
        si = s1[0] + s1[1] + s1[2] + s1[3];
        sp = s2[0] + s2[1] + s2[2] + s2[3];
        const int o = b * PTM1 + tm;
        flag_ws[o] = sc + si;
        // a = floor((cor_sum - inc_sum + 1) / 2)
        a_ws[o] = floorf((sc - si + 1.0f) * 0.5f);
        p_ws[o] = sp;
    }
}

// Kernel 2: one block per batch b. Computes last/start/mask/cnt, writes the
// three masked output arrays, and the per-batch loss term into loss_ws.
__global__ __launch_bounds__(256) void finalize_kernel(
    const float* __restrict__ p_ws,
    const float* __restrict__ flag_ws,
    const float* __restrict__ a_ws,
    const int* __restrict__ isTest,
    const int* __restrict__ testseqlen,
    float* __restrict__ out,        // [0]=loss (written by kernel 3), then p*m, a*m, mask
    float* __restrict__ loss_ws)    // (B,)
{
    const int b = blockIdx.x;

    // last[b] = max t where flag > 0, clamped to >= 0
    int mylast = -1;
    for (int t = threadIdx.x; t < PTM1; t += blockDim.x) {
        if (flag_ws[b * PTM1 + t] > 0.0f) mylast = max(mylast, t);
    }
    for (int off = 32; off > 0; off >>= 1)
        mylast = max(mylast, __shfl_down(mylast, off));
    __shared__ int swl[4];
    __shared__ int s_last;
    const int lane = threadIdx.x & 63;
    const int wv   = threadIdx.x >> 6;
    if (lane == 0) swl[wv] = mylast;
    __syncthreads();
    if (threadIdx.x == 0)
        s_last = max(max(swl[0], swl[1]), max(swl[2], swl[3]));
    __syncthreads();

    const int last = max(s_last, 0);
    int start = 0;
    if (isTest[0]) {
        const int length = last + 1;
        const int tl = testseqlen[0];
        if (length > tl) start = length - tl;
    }
    const float cnt = (float)(last - start + 1);

    float* out_p = out + 1;
    float* out_a = out + 1 + (size_t)PB * PTM1;
    float* out_m = out + 1 + (size_t)2 * PB * PTM1;

    float lsum = 0.0f;
    for (int t = threadIdx.x; t < PTM1; t += blockDim.x) {
        const int o = b * PTM1 + t;
        const bool m = (t >= start) && (t <= last);
        const float p = p_ws[o];
        const float a = a_ws[o];
        out_p[o] = m ? p : 0.0f;
        out_a[o] = m ? a : 0.0f;
        out_m[o] = m ? 1.0f : 0.0f;
        if (m) {
            const float logp  = fmaxf(logf(p), -100.0f);
            const float l1mp  = fmaxf(log1pf(-p), -100.0f);
            lsum += -(a * logp + (1.0f - a) * l1mp);
        }
    }
    for (int off = 32; off > 0; off >>= 1)
        lsum += __shfl_down(lsum, off);
    __shared__ float swf[4];
    if (lane == 0) swf[wv] = lsum;
    __syncthreads();
    if (threadIdx.x == 0) {
        lsum = swf[0] + swf[1] + swf[2] + swf[3];
        loss_ws[b] = lsum / cnt;
    }
}

// Kernel 3: single wave sums the 64 per-batch losses into out[0].
__global__ __launch_bounds__(64) void loss_sum_kernel(
    const float* __restrict__ loss_ws, float* __restrict__ out)
{
    float v = loss_ws[threadIdx.x];
    for (int off = 32; off > 0; off >>= 1)
        v += __shfl_down(v, off);
    if (threadIdx.x == 0) out[0] = v;
}

extern "C" void kernel_launch(void* const* d_in, const int* in_sizes, int n_in,
                              void* d_out, int out_size, void* d_ws, size_t ws_size,
                              hipStream_t stream) {
    const float* pred  = (const float*)d_in[0];
    const float* batch = (const float*)d_in[1];
    const int* isTest     = (const int*)d_in[2];
    const int* testseqlen = (const int*)d_in[3];
    float* out = (float*)d_out;

    // workspace layout: p_ws, flag_ws, a_ws (each B*TM1 floats), loss_ws (B)
    float* p_ws    = (float*)d_ws;
    float* flag_ws = p_ws + (size_t)PB * PTM1;
    float* a_ws    = flag_ws + (size_t)PB * PTM1;
    float* loss_ws = a_ws + (size_t)PB * PTM1;

    const int nrows = PB * PTM1;   // 12736
    row_reduce_kernel<<<nrows, 256, 0, stream>>>(pred, batch, p_ws, flag_ws, a_ws);
    finalize_kernel<<<PB, 256, 0, stream>>>(p_ws, flag_ws, a_ws, isTest, testseqlen,
                                            out, loss_ws);
    loss_sum_kernel<<<1, 64, 0, stream>>>(loss_ws, out);
}

// Round 2
// 614.949 us; speedup vs baseline: 1.0574x; 1.0574x over previous
//
#include <hip/hip_runtime.h>
#include <math.h>

// Problem constants (from reference): B=64, T=200, Q=4096
#define PB 64
#define PT 200
#define PQ 4096
#define PTM1 199

// Kernel 1: one block per (b, t) with t in [1, T-1].
// batch rows are one-hot (at most one nonzero, value 1.0), so we stream ONLY
// batch (417 MB) and gather the single matching pred element (4 B per row)
// instead of streaming pred (saves 209 MB of HBM traffic).
__global__ __launch_bounds__(256) void row_reduce_kernel(
    const float* __restrict__ pred,    // (B, T, Q)
    const float* __restrict__ batch,   // (B, T, 2Q)
    float* __restrict__ p_ws,          // (B, TM1)
    float* __restrict__ flag_ws,       // (B, TM1)
    float* __restrict__ a_ws)          // (B, TM1)
{
    const int bt = blockIdx.x;
    const int b  = bt / PTM1;
    const int tm = bt - b * PTM1;   // 0..198  (output index)
    const int t  = tm + 1;          // batch row index

    const float4* row = (const float4*)(batch + ((size_t)(b * PT + t)) * (2 * PQ));
    const float*  pr  = pred + ((size_t)(b * PT + tm)) * PQ;

    float sc = 0.0f, si = 0.0f, sp = 0.0f;

    // cor half: float4 indices [0, 1024)
    for (int i = threadIdx.x; i < PQ / 4; i += blockDim.x) {
        float4 c = row[i];
        sc += c.x + c.y + c.z + c.w;
        if (c.x != 0.0f || c.y != 0.0f || c.z != 0.0f || c.w != 0.0f) {
            const int base = i << 2;
            if (c.x != 0.0f) sp += c.x * pr[base + 0];
            if (c.y != 0.0f) sp += c.y * pr[base + 1];
            if (c.z != 0.0f) sp += c.z * pr[base + 2];
            if (c.w != 0.0f) sp += c.w * pr[base + 3];
        }
    }
    // inc half: float4 indices [1024, 2048) -> pred index (j - Q)
    for (int i = threadIdx.x + PQ / 4; i < PQ / 2; i += blockDim.x) {
        float4 c = row[i];
        si += c.x + c.y + c.z + c.w;
        if (c.x != 0.0f || c.y != 0.0f || c.z != 0.0f || c.w != 0.0f) {
            const int base = (i << 2) - PQ;
            if (c.x != 0.0f) sp += c.x * pr[base + 0];
            if (c.y != 0.0f) sp += c.y * pr[base + 1];
            if (c.z != 0.0f) sp += c.z * pr[base + 2];
            if (c.w != 0.0f) sp += c.w * pr[base + 3];
        }
    }

    // wave (64-lane) reduction
    for (int off = 32; off > 0; off >>= 1) {
        sc += __shfl_down(sc, off);
        si += __shfl_down(si, off);
        sp += __shfl_down(sp, off);
    }
    __shared__ float s0[4], s1[4], s2[4];
    const int lane = threadIdx.x & 63;
    const int wv   = threadIdx.x >> 6;
    if (lane == 0) { s0[wv] = sc; s1[wv] = si; s2[wv] = sp; }
    __syncthreads();
    if (threadIdx.x == 0) {
        sc = s0[0] + s0[1] + s0[2] + s0[3];
        si = s1[0] + s1[1] + s1[2] + s1[3];
        sp = s2[0] + s2[1] + s2[2] + s2[3];
        const int o = b * PTM1 + tm;
        flag_ws[o] = sc + si;
        // a = floor((cor_sum - inc_sum + 1) / 2)
        a_ws[o] = floorf((sc - si + 1.0f) * 0.5f);
        p_ws[o] = sp;
    }
}

// Kernel 2: one block per batch b. Computes last/start/mask/cnt, writes the
// three masked output arrays, and the per-batch loss term into loss_ws.
__global__ __launch_bounds__(256) void finalize_kernel(
    const float* __restrict__ p_ws,
    const float* __restrict__ flag_ws,
    const float* __restrict__ a_ws,
    const int* __restrict__ isTest,
    const int* __restrict__ testseqlen,
    float* __restrict__ out,        // [0]=loss (written by kernel 3), then p*m, a*m, mask
    float* __restrict__ loss_ws)    // (B,)
{
    const int b = blockIdx.x;

    // last[b] = max t where flag > 0, clamped to >= 0
    int mylast = -1;
    for (int t = threadIdx.x; t < PTM1; t += blockDim.x) {
        if (flag_ws[b * PTM1 + t] > 0.0f) mylast = max(mylast, t);
    }
    for (int off = 32; off > 0; off >>= 1)
        mylast = max(mylast, __shfl_down(mylast, off));
    __shared__ int swl[4];
    __shared__ int s_last;
    const int lane = threadIdx.x & 63;
    const int wv   = threadIdx.x >> 6;
    if (lane == 0) swl[wv] = mylast;
    __syncthreads();
    if (threadIdx.x == 0)
        s_last = max(max(swl[0], swl[1]), max(swl[2], swl[3]));
    __syncthreads();

    const int last = max(s_last, 0);
    int start = 0;
    if (isTest[0]) {
        const int length = last + 1;
        const int tl = testseqlen[0];
        if (length > tl) start = length - tl;
    }
    const float cnt = (float)(last - start + 1);

    float* out_p = out + 1;
    float* out_a = out + 1 + (size_t)PB * PTM1;
    float* out_m = out + 1 + (size_t)2 * PB * PTM1;

    float lsum = 0.0f;
    for (int t = threadIdx.x; t < PTM1; t += blockDim.x) {
        const int o = b * PTM1 + t;
        const bool m = (t >= start) && (t <= last);
        const float p = p_ws[o];
        const float a = a_ws[o];
        out_p[o] = m ? p : 0.0f;
        out_a[o] = m ? a : 0.0f;
        out_m[o] = m ? 1.0f : 0.0f;
        if (m) {
            const float logp  = fmaxf(logf(p), -100.0f);
            const float l1mp  = fmaxf(log1pf(-p), -100.0f);
            lsum += -(a * logp + (1.0f - a) * l1mp);
        }
    }
    for (int off = 32; off > 0; off >>= 1)
        lsum += __shfl_down(lsum, off);
    __shared__ float swf[4];
    if (lane == 0) swf[wv] = lsum;
    __syncthreads();
    if (threadIdx.x == 0) {
        lsum = swf[0] + swf[1] + swf[2] + swf[3];
        loss_ws[b] = lsum / cnt;
    }
}

// Kernel 3: single wave sums the 64 per-batch losses into out[0].
__global__ __launch_bounds__(64) void loss_sum_kernel(
    const float* __restrict__ loss_ws, float* __restrict__ out)
{
    float v = loss_ws[threadIdx.x];
    for (int off = 32; off > 0; off >>= 1)
        v += __shfl_down(v, off);
    if (threadIdx.x == 0) out[0] = v;
}

extern "C" void kernel_launch(void* const* d_in, const int* in_sizes, int n_in,
                              void* d_out, int out_size, void* d_ws, size_t ws_size,
                              hipStream_t stream) {
    const float* pred  = (const float*)d_in[0];
    const float* batch = (const float*)d_in[1];
    const int* isTest     = (const int*)d_in[2];
    const int* testseqlen = (const int*)d_in[3];
    float* out = (float*)d_out;

    // workspace layout: p_ws, flag_ws, a_ws (each B*TM1 floats), loss_ws (B)
    float* p_ws    = (float*)d_ws;
    float* flag_ws = p_ws + (size_t)PB * PTM1;
    float* a_ws    = flag_ws + (size_t)PB * PTM1;
    float* loss_ws = a_ws + (size_t)PB * PTM1;

    const int nrows = PB * PTM1;   // 12736
    row_reduce_kernel<<<nrows, 256, 0, stream>>>(pred, batch, p_ws, flag_ws, a_ws);
    finalize_kernel<<<PB, 256, 0, stream>>>(p_ws, flag_ws, a_ws, isTest, testseqlen,
                                            out, loss_ws);
    loss_sum_kernel<<<1, 64, 0, stream>>>(loss_ws, out);
}